// Round 4
// baseline (245.092 us; speedup 1.0000x reference)
//
#include <hip/hip_runtime.h>

typedef __attribute__((ext_vector_type(4))) float  f32x4;
typedef __attribute__((ext_vector_type(8))) short  s16x8;
typedef __attribute__((ext_vector_type(4))) unsigned int u32x4;
typedef __attribute__((ext_vector_type(2))) unsigned int u32x2;
typedef __attribute__((ext_vector_type(4))) unsigned short u16x4;

#define NB 8
#define NT 2048
#define NC 1024
#define NH 128
#define NM (NB * NT)

__device__ __forceinline__ unsigned short f2bf(float f) {
  union { float f; unsigned u; } v; v.f = f;
  unsigned r = v.u + 0x7FFFu + ((v.u >> 16) & 1u);  // RNE
  return (unsigned short)(r >> 16);
}
__device__ __forceinline__ unsigned pack2(float a, float b) {
  return (unsigned)f2bf(a) | ((unsigned)f2bf(b) << 16);
}
__device__ __forceinline__ f32x4 mfma16(s16x8 a, s16x8 b, f32x4 c) {
  return __builtin_amdgcn_mfma_f32_16x16x32_bf16(a, b, c, 0, 0, 0);
}

// ---------------- kernel 0: W -> bf16 transposed [3][128][1024], both sides coalesced
__global__ __launch_bounds__(256) void k_prep_w(
    const float* __restrict__ wq, const float* __restrict__ wk,
    const float* __restrict__ wv, unsigned short* __restrict__ wt3) {
  __shared__ float ts[64][65];
  const int tid = threadIdx.x;
  const int w = blockIdx.x >> 5;
  const int rem = blockIdx.x & 31;
  const int c0 = (rem >> 1) * 64;
  const int h0 = (rem & 1) * 64;
  const float* W = (w == 0) ? wq : (w == 1) ? wk : wv;
  const int hl = tid & 63, ci = tid >> 6;
  #pragma unroll
  for (int i = 0; i < 16; ++i) {
    int cl = i * 4 + ci;
    ts[cl][hl] = W[(size_t)(c0 + cl) * NH + h0 + hl];
  }
  __syncthreads();
  const int cl2 = tid & 63, hi2 = tid >> 6;
  #pragma unroll
  for (int j = 0; j < 16; ++j) {
    int hl2 = j * 4 + hi2;
    float v = ts[cl2][hl2];
    if (w == 0) v *= 0.08838834764831845f;
    wt3[(size_t)w * 131072 + (size_t)(h0 + hl2) * NC + c0 + cl2] = f2bf(v);
  }
}

// ---------------- kernel 1: q,k,v projections. BM=32, 8 waves (nstrip=48), grid 512
// -> 2 blocks/CU, 16 waves/CU. x fp32->bf16 into 8KB dbuf swizzled LDS; W from L2.
__global__ __launch_bounds__(512, 4) void k_qkv(
    const float* __restrict__ x, const unsigned short* __restrict__ wt3,
    unsigned short* __restrict__ qo, unsigned short* __restrict__ ko,
    unsigned short* __restrict__ vo) {
  __shared__ u32x4 xs4[8192 / 16];           // 2 bufs x [32 rows][128B] swizzled
  char* xs = (char*)xs4;
  const int tid = threadIdx.x;
  const int lane = tid & 63;
  const int w = tid >> 6;                    // 0..7
  const int m0 = blockIdx.x * 32;
  const int c15 = lane & 15;
  const int g4 = lane >> 4;

  const int sr = tid >> 4;                   // staging row 0..31
  const float* xp = x + (size_t)(m0 + sr) * NC + (tid & 15) * 4;
  const int wb = (sr * 128 + (tid & 15) * 8) ^ ((sr & 7) << 4);

  const int n0 = w * 48;                     // wave n-strip
  const int aswz = (c15 & 7) << 4;
  const int akb = g4 * 16;

  f32x4 acc[2][3] = {};
  f32x4 xr = *(const f32x4*)(xp);
  {
    u32x2 pk = { pack2(xr.x, xr.y), pack2(xr.z, xr.w) };
    *(u32x2*)(xs + wb) = pk;                 // buf 0
  }
  __syncthreads();

  for (int kt = 0; kt < 16; ++kt) {
    if (kt < 15) xr = *(const f32x4*)(xp + (kt + 1) * 64);   // T14: issue early
    char* cb = xs + (kt & 1) * 4096;
    #pragma unroll
    for (int ks = 0; ks < 2; ++ks) {
      s16x8 a0 = *(const s16x8*)(cb + (((c15)      * 128 + ks * 64 + akb) ^ aswz));
      s16x8 a1 = *(const s16x8*)(cb + (((c15 + 16) * 128 + ks * 64 + akb) ^ aswz));
      const unsigned short* wp = wt3 + (size_t)(n0 + c15) * NC
                                 + kt * 64 + ks * 32 + g4 * 8;
      #pragma unroll
      for (int nj = 0; nj < 3; ++nj) {
        s16x8 bf = *(const s16x8*)(wp + (size_t)nj * 16 * NC);
        acc[0][nj] = mfma16(a0, bf, acc[0][nj]);
        acc[1][nj] = mfma16(a1, bf, acc[1][nj]);
      }
    }
    if (kt < 15) {                           // write late (after compute cover)
      u32x2 pk = { pack2(xr.x, xr.y), pack2(xr.z, xr.w) };
      *(u32x2*)(xs + ((kt + 1) & 1) * 4096 + wb) = pk;
    }
    __syncthreads();
  }
  // epilogue: q,k row-major [M][128]; v transposed [B][128][T]
  const int rl = g4 * 4;
  #pragma unroll
  for (int m = 0; m < 2; ++m) {
    #pragma unroll
    for (int nj = 0; nj < 3; ++nj) {
      f32x4 a = acc[m][nj];
      int gcol = n0 + nj * 16 + c15;
      int gr = m0 + m * 16 + rl;
      int h = gcol & 127;
      if (gcol < 256) {
        unsigned short* dst = (gcol < 128) ? qo : ko;
        dst[(size_t)(gr + 0) * NH + h] = f2bf(a.x);
        dst[(size_t)(gr + 1) * NH + h] = f2bf(a.y);
        dst[(size_t)(gr + 2) * NH + h] = f2bf(a.z);
        dst[(size_t)(gr + 3) * NH + h] = f2bf(a.w);
      } else {
        int bb = gr >> 11, tt = gr & 2047;
        u16x4 pv = { f2bf(a.x), f2bf(a.y), f2bf(a.z), f2bf(a.w) };
        *(u16x4*)(vo + ((size_t)(bb * NH + h) * NT + tt)) = pv;
      }
    }
  }
}

// ---------------- kernel 2: flash attention, kv-split x4 in-block.
// QBLK=32: 8 waves = 2 q-subtiles x 4 kv-groups; grp owns kv quarter (512), KVBLK=32,
// single-buffer K/V (73KB LDS) -> grid 512, 2 blocks/CU, 16 waves/CU. 4-way LDS merge.
__global__ __launch_bounds__(512, 4) void k_attn(
    const unsigned short* __restrict__ qg, const unsigned short* __restrict__ kg,
    const unsigned short* __restrict__ vg, float* __restrict__ out) {
  __shared__ u32x4 lds4[74752 / 16];
  char* L = (char*)lds4;
  const int tid = threadIdx.x;
  const int lane = tid & 63;
  const int w = tid >> 6;                    // 0..7
  const int grp = w & 3;                     // kv quarter
  const int qs = w >> 2;                     // q sub-tile (16 rows)
  const int gl = qs * 64 + lane;             // grp-local thread 0..127
  const int b = blockIdx.y;
  const int qr0 = blockIdx.x * 32;
  const int c15 = lane & 15;
  const int g4 = lane >> 4;
  const int kv0 = grp * 512;

  char* Kg = L + grp * 16384;                // [32 kv][256B] swizzled (8KB)
  char* Vg = Kg + 8192;                      // [128 h][32 kv] packed [64 rr][128B] (8KB)
  char* pw = L + 65536 + w * 1024;           // per-wave P packed [8 pr][128B]
  float* msh = (float*)(L + 73728);          // [3][32]
  float* lsh = msh + 96;                     // [3][32]

  s16x8 qf[4];
  #pragma unroll
  for (int ks = 0; ks < 4; ++ks)
    qf[ks] = *(const s16x8*)(qg + (size_t)(b * NT + qr0 + qs * 16 + c15) * NH + ks * 32 + g4 * 8);

  float m_run[4], lsum[4];
  #pragma unroll
  for (int r = 0; r < 4; ++r) { m_run[r] = -3.0e38f; lsum[r] = 0.0f; }
  f32x4 acc_o[8] = {};

  // staging: grp's 128 threads. K: [32 kv][128 h]; V src transposed [128 h][T].
  const int krow = gl >> 4;                  // 0..7 (+8i)
  const unsigned short* kptr = kg + (size_t)(b * NT + kv0 + krow) * NH + (gl & 15) * 8;
  const int vh = gl >> 2;                    // 0..31 (+32i)
  const unsigned short* vptr = vg + (size_t)(b * NH + vh) * NT + kv0 + (gl & 3) * 8;

  u32x4 kreg[4], vreg[4];
  #pragma unroll
  for (int i = 0; i < 4; ++i) {
    kreg[i] = *(const u32x4*)(kptr + (size_t)(i * 8) * NH);
    vreg[i] = *(const u32x4*)(vptr + (size_t)(i * 32) * NT);
  }
  auto write_tiles = [&]() {
    #pragma unroll
    for (int i = 0; i < 4; ++i) {
      int r = krow + i * 8;
      *(u32x4*)(Kg + ((r * 256 + (gl & 15) * 16) ^ ((r & 7) << 4))) = kreg[i];
      int h = vh + i * 32;
      int rr = h >> 1;
      *(u32x4*)(Vg + ((rr * 128 + (h & 1) * 64 + (gl & 3) * 16) ^ ((rr & 7) << 4))) = vreg[i];
    }
  };
  write_tiles();
  __syncthreads();

  for (int kt = 0; kt < 16; ++kt) {
    if (kt < 15) {                           // T14: issue next tile loads early
      #pragma unroll
      for (int i = 0; i < 4; ++i) {
        kreg[i] = *(const u32x4*)(kptr + (size_t)((kt + 1) * 32 + i * 8) * NH);
        vreg[i] = *(const u32x4*)(vptr + (size_t)(i * 32) * NT + (kt + 1) * 32);
      }
    }
    // S = Q K^T  -> [16 q][32 kv]
    f32x4 s[2] = {};
    __builtin_amdgcn_s_setprio(1);
    #pragma unroll
    for (int nj = 0; nj < 2; ++nj) {
      int kr = nj * 16 + c15;
      #pragma unroll
      for (int ks = 0; ks < 4; ++ks) {
        s16x8 bf = *(const s16x8*)(Kg + ((kr * 256 + ks * 64 + g4 * 16) ^ ((kr & 7) << 4)));
        s[nj] = mfma16(qf[ks], bf, s[nj]);
      }
    }
    __builtin_amdgcn_s_setprio(0);
    // online softmax (row in 16-lane group); l deferred per-lane
    float alpha[4];
    #pragma unroll
    for (int r = 0; r < 4; ++r) {
      float pm = fmaxf(s[0][r], s[1][r]);
      pm = fmaxf(pm, __shfl_xor(pm, 1));
      pm = fmaxf(pm, __shfl_xor(pm, 2));
      pm = fmaxf(pm, __shfl_xor(pm, 4));
      pm = fmaxf(pm, __shfl_xor(pm, 8));
      float mn = fmaxf(m_run[r], pm);
      alpha[r] = __expf(m_run[r] - mn);
      m_run[r] = mn;
      float e0 = __expf(s[0][r] - mn);
      float e1 = __expf(s[1][r] - mn);
      s[0][r] = e0; s[1][r] = e1;
      lsum[r] = lsum[r] * alpha[r] + (e0 + e1);
    }
    #pragma unroll
    for (int hj = 0; hj < 8; ++hj) {
      acc_o[hj][0] *= alpha[0]; acc_o[hj][1] *= alpha[1];
      acc_o[hj][2] *= alpha[2]; acc_o[hj][3] *= alpha[3];
    }
    // P -> per-wave LDS (packed rows), wave-local (no barrier needed)
    #pragma unroll
    for (int nj = 0; nj < 2; ++nj) {
      #pragma unroll
      for (int r = 0; r < 4; ++r) {
        int row = g4 * 4 + r;
        int pr = row >> 1;
        *(unsigned short*)(pw + ((pr * 128 + (row & 1) * 64 + (nj * 16 + c15) * 2)
                                 ^ ((pr & 7) << 4))) = f2bf(s[nj][r]);
      }
    }
    // O += P V   (k=32 -> one MFMA per hj)
    __builtin_amdgcn_s_setprio(1);
    {
      int ppr = c15 >> 1;
      s16x8 pa = *(const s16x8*)(pw + ((ppr * 128 + (c15 & 1) * 64 + g4 * 16) ^ ((ppr & 7) << 4)));
      #pragma unroll
      for (int hj = 0; hj < 8; ++hj) {
        int rr = hj * 8 + (c15 >> 1);
        s16x8 bv = *(const s16x8*)(Vg + ((rr * 128 + (c15 & 1) * 64 + g4 * 16) ^ ((rr & 7) << 4)));
        acc_o[hj] = mfma16(pa, bv, acc_o[hj]);
      }
    }
    __builtin_amdgcn_s_setprio(0);
    __syncthreads();                         // all waves done reading K/V
    if (kt < 15) write_tiles();              // vmcnt wait here (1 phase of cover)
    __syncthreads();
  }
  // finish deferred l
  float l_run[4];
  #pragma unroll
  for (int r = 0; r < 4; ++r) {
    float ls = lsum[r];
    ls += __shfl_xor(ls, 1);
    ls += __shfl_xor(ls, 2);
    ls += __shfl_xor(ls, 4);
    ls += __shfl_xor(ls, 8);
    l_run[r] = ls;
  }
  // 4-way merge through LDS (reuse K/V region; loop ended with barrier)
  if (grp > 0) {
    char* mb = L + (grp - 1) * 16384;        // [32 rows][128 h] f32
    #pragma unroll
    for (int r = 0; r < 4; ++r) {
      int row = qs * 16 + g4 * 4 + r;
      #pragma unroll
      for (int hj = 0; hj < 8; ++hj)
        *(float*)(mb + row * 512 + (hj * 16 + c15) * 4) = acc_o[hj][r];
      if (c15 == 0) {
        msh[(grp - 1) * 32 + row] = m_run[r];
        lsh[(grp - 1) * 32 + row] = l_run[r];
      }
    }
  }
  __syncthreads();
  if (grp == 0) {
    #pragma unroll
    for (int r = 0; r < 4; ++r) {
      int row = qs * 16 + g4 * 4 + r;
      float M = m_run[r];
      float mg[3], lg[3];
      #pragma unroll
      for (int g = 0; g < 3; ++g) {
        mg[g] = msh[g * 32 + row];
        lg[g] = lsh[g * 32 + row];
        M = fmaxf(M, mg[g]);
      }
      float w0 = __expf(m_run[r] - M);
      float wg[3];
      float den = w0 * l_run[r];
      #pragma unroll
      for (int g = 0; g < 3; ++g) { wg[g] = __expf(mg[g] - M); den += wg[g] * lg[g]; }
      float inv = 1.0f / den;
      #pragma unroll
      for (int hj = 0; hj < 8; ++hj) {
        float o = w0 * acc_o[hj][r];
        #pragma unroll
        for (int g = 0; g < 3; ++g)
          o += wg[g] * *(const float*)(L + g * 16384 + row * 512 + (hj * 16 + c15) * 4);
        out[(size_t)(b * NT + qr0 + row) * NH + hj * 16 + c15] = o * inv;
      }
    }
  }
}

extern "C" void kernel_launch(void* const* d_in, const int* in_sizes, int n_in,
                              void* d_out, int out_size, void* d_ws, size_t ws_size,
                              hipStream_t stream) {
  const float* x  = (const float*)d_in[0];
  const float* wq = (const float*)d_in[1];
  const float* wk = (const float*)d_in[2];
  const float* wv = (const float*)d_in[3];
  unsigned short* ws  = (unsigned short*)d_ws;
  unsigned short* qb  = ws;                           // [M][128] bf16   (4MB)
  unsigned short* kb  = ws + (size_t)2 * 1024 * 1024; // [M][128] bf16   (4MB)
  unsigned short* vb  = ws + (size_t)4 * 1024 * 1024; // [B][128][T] bf16 (4MB)
  unsigned short* wt3 = ws + (size_t)6 * 1024 * 1024; // [3][128][1024] bf16 (0.75MB)

  k_prep_w<<<dim3(96), dim3(256), 0, stream>>>(wq, wk, wv, wt3);
  k_qkv<<<dim3(NM / 32), dim3(512), 0, stream>>>(x, wt3, qb, kb, vb);
  k_attn<<<dim3(NT / 32, NB), dim3(512), 0, stream>>>(qb, kb, vb, (float*)d_out);
}

// Round 6
// 191.561 us; speedup vs baseline: 1.2794x; 1.2794x over previous
//
#include <hip/hip_runtime.h>

typedef __attribute__((ext_vector_type(4))) float  f32x4;
typedef __attribute__((ext_vector_type(8))) short  s16x8;
typedef __attribute__((ext_vector_type(4))) unsigned int u32x4;
typedef __attribute__((ext_vector_type(4))) unsigned short u16x4;

#define NB 8
#define NT 2048
#define NC 1024
#define NH 128
#define NM (NB * NT)

__device__ __forceinline__ unsigned short f2bf(float f) {
  union { float f; unsigned u; } v; v.f = f;
  unsigned r = v.u + 0x7FFFu + ((v.u >> 16) & 1u);  // RNE
  return (unsigned short)(r >> 16);
}
__device__ __forceinline__ unsigned pack2(float a, float b) {
  return (unsigned)f2bf(a) | ((unsigned)f2bf(b) << 16);
}
__device__ __forceinline__ f32x4 mfma16(s16x8 a, s16x8 b, f32x4 c) {
  return __builtin_amdgcn_mfma_f32_16x16x32_bf16(a, b, c, 0, 0, 0);
}

// ---------------- kernel 0: W -> bf16 transposed [3][128][1024], both sides coalesced
__global__ __launch_bounds__(256) void k_prep_w(
    const float* __restrict__ wq, const float* __restrict__ wk,
    const float* __restrict__ wv, unsigned short* __restrict__ wt3) {
  __shared__ float ts[64][65];
  const int tid = threadIdx.x;
  const int w = blockIdx.x >> 5;
  const int rem = blockIdx.x & 31;
  const int c0 = (rem >> 1) * 64;
  const int h0 = (rem & 1) * 64;
  const float* W = (w == 0) ? wq : (w == 1) ? wk : wv;
  const int hl = tid & 63, ci = tid >> 6;
  #pragma unroll
  for (int i = 0; i < 16; ++i) {
    int cl = i * 4 + ci;
    ts[cl][hl] = W[(size_t)(c0 + cl) * NH + h0 + hl];
  }
  __syncthreads();
  const int cl2 = tid & 63, hi2 = tid >> 6;
  #pragma unroll
  for (int j = 0; j < 16; ++j) {
    int hl2 = j * 4 + hi2;
    float v = ts[cl2][hl2];
    if (w == 0) v *= 0.08838834764831845f;
    wt3[(size_t)w * 131072 + (size_t)(h0 + hl2) * NC + c0 + cl2] = f2bf(v);
  }
}

// ---------------- kernel 1: q,k,v projections. BM=32, BK=128, 4 waves, grid 512
// (2 independent blocks/CU). 4x f32x4 x-prefetch per thread per iter (deep MLP).
__global__ __launch_bounds__(256, 3) void k_qkv(
    const float* __restrict__ x, const unsigned short* __restrict__ wt3,
    unsigned short* __restrict__ qo, unsigned short* __restrict__ ko,
    unsigned short* __restrict__ vo) {
  __shared__ u32x4 xs4[16384 / 16];          // 2 bufs x [32 rows][256B bf16] swizzled
  char* xs = (char*)xs4;
  const int tid = threadIdx.x;
  const int lane = tid & 63;
  const int w = tid >> 6;                    // 0..3
  const int m0 = blockIdx.x * 32;
  const int c15 = lane & 15;
  const int g4 = lane >> 4;

  const int sr = tid >> 3;                   // staging row 0..31 (8 thr/row)
  const float* xp = x + (size_t)(m0 + sr) * NC + (tid & 7) * 16;
  const int wb = (sr * 256 + (tid & 7) * 32) ^ ((sr & 7) << 4);

  const int n0 = w * 96;
  const int aswz = (c15 & 7) << 4;

  f32x4 acc[2][6] = {};
  f32x4 xr[4];
  #pragma unroll
  for (int j = 0; j < 4; ++j) xr[j] = *(const f32x4*)(xp + j * 4);
  auto pack_write = [&](int buf) {
    u32x4 gA = { pack2(xr[0].x, xr[0].y), pack2(xr[0].z, xr[0].w),
                 pack2(xr[1].x, xr[1].y), pack2(xr[1].z, xr[1].w) };
    u32x4 gB = { pack2(xr[2].x, xr[2].y), pack2(xr[2].z, xr[2].w),
                 pack2(xr[3].x, xr[3].y), pack2(xr[3].z, xr[3].w) };
    *(u32x4*)(xs + buf * 8192 + wb) = gA;
    *(u32x4*)(xs + buf * 8192 + ((sr * 256 + (tid & 7) * 32 + 16) ^ ((sr & 7) << 4))) = gB;
  };
  pack_write(0);
  __syncthreads();

  for (int kt = 0; kt < 8; ++kt) {
    if (kt < 7) {                            // deep prefetch: 4x16B in flight
      #pragma unroll
      for (int j = 0; j < 4; ++j) xr[j] = *(const f32x4*)(xp + (kt + 1) * 128 + j * 4);
    }
    char* cb = xs + (kt & 1) * 8192;
    #pragma unroll
    for (int ks = 0; ks < 4; ++ks) {
      s16x8 a0 = *(const s16x8*)(cb + (((c15)      * 256 + ks * 64 + g4 * 16) ^ aswz));
      s16x8 a1 = *(const s16x8*)(cb + (((c15 + 16) * 256 + ks * 64 + g4 * 16) ^ aswz));
      const unsigned short* wp = wt3 + (size_t)(n0 + c15) * NC
                                 + kt * 128 + ks * 32 + g4 * 8;
      #pragma unroll
      for (int nj = 0; nj < 6; ++nj) {
        s16x8 bf = *(const s16x8*)(wp + (size_t)nj * 16 * NC);
        acc[0][nj] = mfma16(a0, bf, acc[0][nj]);
        acc[1][nj] = mfma16(a1, bf, acc[1][nj]);
      }
    }
    if (kt < 7) pack_write((kt + 1) & 1);    // vmcnt wait here, after compute cover
    __syncthreads();                         // single barrier per iter (dbuf)
  }
  // epilogue: q,k row-major [M][128]; v transposed [B][128][T]
  const int rl = g4 * 4;
  #pragma unroll
  for (int m = 0; m < 2; ++m) {
    #pragma unroll
    for (int nj = 0; nj < 6; ++nj) {
      f32x4 a = acc[m][nj];
      int gcol = n0 + nj * 16 + c15;
      int gr = m0 + m * 16 + rl;
      int h = gcol & 127;
      if (gcol < 256) {
        unsigned short* dst = (gcol < 128) ? qo : ko;
        dst[(size_t)(gr + 0) * NH + h] = f2bf(a.x);
        dst[(size_t)(gr + 1) * NH + h] = f2bf(a.y);
        dst[(size_t)(gr + 2) * NH + h] = f2bf(a.z);
        dst[(size_t)(gr + 3) * NH + h] = f2bf(a.w);
      } else {
        int bb = gr >> 11, tt = gr & 2047;
        u16x4 pv = { f2bf(a.x), f2bf(a.y), f2bf(a.z), f2bf(a.w) };
        *(u16x4*)(vo + ((size_t)(bb * NH + h) * NT + tt)) = pv;
      }
    }
  }
}

// ---------------- kernel 2: flash attention. QBLK=64, kv-split x2, KVBLK=128.
// 8 waves = 4 q-subtiles x 2 kv-groups; 8 iters total; 64 MFMA/iter/wave.
// Staging 16x u32x4 per thread (256B in flight). Single K/V buffer, 2 barriers/iter.
__global__ __launch_bounds__(512, 2) void k_attn(
    const unsigned short* __restrict__ qg, const unsigned short* __restrict__ kg,
    const unsigned short* __restrict__ vg, float* __restrict__ out) {
  __shared__ u32x4 lds4[147456 / 16];        // 144KB
  char* L = (char*)lds4;
  const int tid = threadIdx.x;
  const int lane = tid & 63;
  const int w = tid >> 6;                    // 0..7
  const int grp = w & 1;                     // kv half
  const int qs = w >> 1;                     // q sub-tile (16 rows)
  const int gl = qs * 64 + lane;             // group-local 0..255
  const int b = blockIdx.y;
  const int qr0 = blockIdx.x * 64;
  const int c15 = lane & 15;
  const int g4 = lane >> 4;
  const int kv0 = grp * 1024;

  char* Kg = L + grp * 65536;                // [128 kv][256B] swizzled (32KB)
  char* Vg = Kg + 32768;                     // [128 h][256B kv] swizzled (32KB)
  char* pw = L + 131072 + w * 2048;          // per-wave P [16 q][64 kv] swizzled

  s16x8 qf[4];
  #pragma unroll
  for (int ks = 0; ks < 4; ++ks)
    qf[ks] = *(const s16x8*)(qg + (size_t)(b * NT + qr0 + qs * 16 + c15) * NH + ks * 32 + g4 * 8);

  float m_run[4], lsum[4];
  #pragma unroll
  for (int r = 0; r < 4; ++r) { m_run[r] = -3.0e38f; lsum[r] = 0.0f; }
  f32x4 acc_o[8] = {};

  const int srow = gl >> 4;                  // 0..15 (+16i)
  const unsigned short* kptr = kg + (size_t)(b * NT + kv0 + srow) * NH + (gl & 15) * 8;
  const unsigned short* vptr = vg + (size_t)(b * NH + srow) * NT + kv0 + (gl & 15) * 8;

  u32x4 kreg[8], vreg[8];
  auto stage = [&](int kt) {
    #pragma unroll
    for (int i = 0; i < 8; ++i) {
      kreg[i] = *(const u32x4*)(kptr + ((size_t)(kt * 128 + i * 16)) * NH);
      vreg[i] = *(const u32x4*)(vptr + (size_t)(i * 16) * NT + kt * 128);
    }
  };
  auto write_tiles = [&]() {
    #pragma unroll
    for (int i = 0; i < 8; ++i) {
      int r = srow + i * 16;
      int off = (r * 256 + (gl & 15) * 16) ^ ((r & 7) << 4);
      *(u32x4*)(Kg + off) = kreg[i];
      *(u32x4*)(Vg + off) = vreg[i];
    }
  };
  stage(0);
  write_tiles();
  __syncthreads();

  for (int kt = 0; kt < 8; ++kt) {
    if (kt < 7) stage(kt + 1);               // 16x16B in flight across compute
    // S = Q K^T -> [16 q][128 kv]
    f32x4 s[8];
    __builtin_amdgcn_s_setprio(1);
    #pragma unroll
    for (int nj = 0; nj < 8; ++nj) {
      f32x4 acc_s = {};
      int kr = nj * 16 + c15;
      int kswz = (kr & 7) << 4;
      #pragma unroll
      for (int ks = 0; ks < 4; ++ks) {
        s16x8 bf = *(const s16x8*)(Kg + ((kr * 256 + ks * 64 + g4 * 16) ^ kswz));
        acc_s = mfma16(qf[ks], bf, acc_s);
      }
      s[nj] = acc_s;
    }
    __builtin_amdgcn_s_setprio(0);
    // online softmax (row in 16-lane group), deferred l
    float alpha[4];
    #pragma unroll
    for (int r = 0; r < 4; ++r) {
      float pm = fmaxf(fmaxf(fmaxf(s[0][r], s[1][r]), fmaxf(s[2][r], s[3][r])),
                       fmaxf(fmaxf(s[4][r], s[5][r]), fmaxf(s[6][r], s[7][r])));
      pm = fmaxf(pm, __shfl_xor(pm, 1));
      pm = fmaxf(pm, __shfl_xor(pm, 2));
      pm = fmaxf(pm, __shfl_xor(pm, 4));
      pm = fmaxf(pm, __shfl_xor(pm, 8));
      float mn = fmaxf(m_run[r], pm);
      alpha[r] = __expf(m_run[r] - mn);
      m_run[r] = mn;
      float psum = 0.0f;
      #pragma unroll
      for (int nj = 0; nj < 8; ++nj) {
        float e = __expf(s[nj][r] - mn);
        s[nj][r] = e;
        psum += e;
      }
      lsum[r] = lsum[r] * alpha[r] + psum;
    }
    #pragma unroll
    for (int hj = 0; hj < 8; ++hj) {
      acc_o[hj][0] *= alpha[0]; acc_o[hj][1] *= alpha[1];
      acc_o[hj][2] *= alpha[2]; acc_o[hj][3] *= alpha[3];
    }
    // two P halves of 64 kv each; P write is wave-local (no barrier)
    #pragma unroll
    for (int half = 0; half < 2; ++half) {
      #pragma unroll
      for (int nj = 0; nj < 4; ++nj) {
        #pragma unroll
        for (int r = 0; r < 4; ++r) {
          int row = g4 * 4 + r;
          *(unsigned short*)(pw + ((row * 128 + (nj * 16 + c15) * 2) ^ ((row & 7) << 4)))
              = f2bf(s[half * 4 + nj][r]);
        }
      }
      __builtin_amdgcn_s_setprio(1);
      #pragma unroll
      for (int ks2 = 0; ks2 < 2; ++ks2) {
        s16x8 pa = *(const s16x8*)(pw + ((c15 * 128 + ks2 * 64 + g4 * 16) ^ ((c15 & 7) << 4)));
        int vcb = (half * 2 + ks2) * 64 + g4 * 16;
        #pragma unroll
        for (int hj = 0; hj < 8; ++hj) {
          int vr = hj * 16 + c15;
          s16x8 bv = *(const s16x8*)(Vg + ((vr * 256 + vcb) ^ ((vr & 7) << 4)));
          acc_o[hj] = mfma16(pa, bv, acc_o[hj]);
        }
      }
      __builtin_amdgcn_s_setprio(0);
    }
    __syncthreads();                         // all waves done with K/V
    if (kt < 7) write_tiles();               // vmcnt wait (covered by compute)
    __syncthreads();
  }
  // finish deferred l
  float l_run[4];
  #pragma unroll
  for (int r = 0; r < 4; ++r) {
    float ls = lsum[r];
    ls += __shfl_xor(ls, 1);
    ls += __shfl_xor(ls, 2);
    ls += __shfl_xor(ls, 4);
    ls += __shfl_xor(ls, 8);
    l_run[r] = ls;
  }
  // 2-way merge through LDS
  float* msh = (float*)(L + 131072);         // 64 rows
  float* lsh = msh + 64;
  if (grp == 1) {
    #pragma unroll
    for (int r = 0; r < 4; ++r) {
      int row = qs * 16 + g4 * 4 + r;
      #pragma unroll
      for (int hj = 0; hj < 8; ++hj)
        *(float*)(L + row * 512 + (hj * 16 + c15) * 4) = acc_o[hj][r];
      if (c15 == 0) { msh[row] = m_run[r]; lsh[row] = l_run[r]; }
    }
  }
  __syncthreads();
  if (grp == 0) {
    #pragma unroll
    for (int r = 0; r < 4; ++r) {
      int row = qs * 16 + g4 * 4 + r;
      float m1 = msh[row], l1 = lsh[row];
      float M = fmaxf(m_run[r], m1);
      float w0 = __expf(m_run[r] - M);
      float w1 = __expf(m1 - M);
      float den = 1.0f / (w0 * l_run[r] + w1 * l1);
      #pragma unroll
      for (int hj = 0; hj < 8; ++hj) {
        float o1 = *(const float*)(L + row * 512 + (hj * 16 + c15) * 4);
        out[(size_t)(b * NT + qr0 + row) * NH + hj * 16 + c15] =
            (w0 * acc_o[hj][r] + w1 * o1) * den;
      }
    }
  }
}

extern "C" void kernel_launch(void* const* d_in, const int* in_sizes, int n_in,
                              void* d_out, int out_size, void* d_ws, size_t ws_size,
                              hipStream_t stream) {
  const float* x  = (const float*)d_in[0];
  const float* wq = (const float*)d_in[1];
  const float* wk = (const float*)d_in[2];
  const float* wv = (const float*)d_in[3];
  unsigned short* ws  = (unsigned short*)d_ws;
  unsigned short* qb  = ws;                           // [M][128] bf16   (4MB)
  unsigned short* kb  = ws + (size_t)2 * 1024 * 1024; // [M][128] bf16   (4MB)
  unsigned short* vb  = ws + (size_t)4 * 1024 * 1024; // [B][128][T] bf16 (4MB)
  unsigned short* wt3 = ws + (size_t)6 * 1024 * 1024; // [3][128][1024] bf16 (0.75MB)

  k_prep_w<<<dim3(96), dim3(256), 0, stream>>>(wq, wk, wv, wt3);
  k_qkv<<<dim3(NM / 32), dim3(256), 0, stream>>>(x, wt3, qb, kb, vb);
  k_attn<<<dim3(NT / 64, NB), dim3(512), 0, stream>>>(qb, kb, vb, (float*)d_out);
}

// Round 7
// 183.984 us; speedup vs baseline: 1.3321x; 1.0412x over previous
//
#include <hip/hip_runtime.h>

typedef __attribute__((ext_vector_type(4))) float  f32x4;
typedef __attribute__((ext_vector_type(8))) short  s16x8;
typedef __attribute__((ext_vector_type(4))) unsigned int u32x4;
typedef __attribute__((ext_vector_type(4))) unsigned short u16x4;

#define NB 8
#define NT 2048
#define NC 1024
#define NH 128
#define NM (NB * NT)

__device__ __forceinline__ unsigned short f2bf(float f) {
  union { float f; unsigned u; } v; v.f = f;
  unsigned r = v.u + 0x7FFFu + ((v.u >> 16) & 1u);  // RNE
  return (unsigned short)(r >> 16);
}
__device__ __forceinline__ unsigned pack2(float a, float b) {
  return (unsigned)f2bf(a) | ((unsigned)f2bf(b) << 16);
}
__device__ __forceinline__ f32x4 mfma16(s16x8 a, s16x8 b, f32x4 c) {
  return __builtin_amdgcn_mfma_f32_16x16x32_bf16(a, b, c, 0, 0, 0);
}

// ---------------- kernel 0: W -> bf16 transposed [3][128][1024], both sides coalesced
__global__ __launch_bounds__(256) void k_prep_w(
    const float* __restrict__ wq, const float* __restrict__ wk,
    const float* __restrict__ wv, unsigned short* __restrict__ wt3) {
  __shared__ float ts[64][65];
  const int tid = threadIdx.x;
  const int w = blockIdx.x >> 5;
  const int rem = blockIdx.x & 31;
  const int c0 = (rem >> 1) * 64;
  const int h0 = (rem & 1) * 64;
  const float* W = (w == 0) ? wq : (w == 1) ? wk : wv;
  const int hl = tid & 63, ci = tid >> 6;
  #pragma unroll
  for (int i = 0; i < 16; ++i) {
    int cl = i * 4 + ci;
    ts[cl][hl] = W[(size_t)(c0 + cl) * NH + h0 + hl];
  }
  __syncthreads();
  const int cl2 = tid & 63, hi2 = tid >> 6;
  #pragma unroll
  for (int j = 0; j < 16; ++j) {
    int hl2 = j * 4 + hi2;
    float v = ts[cl2][hl2];
    if (w == 0) v *= 0.08838834764831845f;
    wt3[(size_t)w * 131072 + (size_t)(h0 + hl2) * NC + c0 + cl2] = f2bf(v);
  }
}

// ---------------- kernel 1: q,k,v projections. BM=128, BN=192, BK=64; grid (128,2)
// = 1 block/CU, 8 waves = 2 m-halves x 4 n-strips. W-frags upfront into wf[] (deep
// L2 concurrency); W L2 traffic 196 MB (was 393). x fp32->bf16 dbuf swizzled LDS.
__global__ __launch_bounds__(512, 2) void k_qkv(
    const float* __restrict__ x, const unsigned short* __restrict__ wt3,
    unsigned short* __restrict__ qo, unsigned short* __restrict__ ko,
    unsigned short* __restrict__ vo) {
  __shared__ u32x4 xs4[32768 / 16];          // 2 bufs x [128 rows][128B] swizzled
  char* xs = (char*)xs4;
  const int tid = threadIdx.x;
  const int lane = tid & 63;
  const int w = tid >> 6;                    // 0..7
  const int mg = w >> 2;                     // 0..1 (64-row m-half)
  const int ng = w & 3;                      // 0..3 (48-col n-strip)
  const int m0 = blockIdx.x * 128;
  const int n0 = blockIdx.y * 192 + ng * 48;
  const int c15 = lane & 15;
  const int g4 = lane >> 4;

  const int sr = tid >> 2;                   // staging row 0..127 (4 thr/row)
  const float* xp = x + (size_t)(m0 + sr) * NC + (tid & 3) * 16;
  const int wbA = (sr * 128 + (tid & 3) * 32) ^ ((sr & 7) << 4);
  const int wbB = (sr * 128 + (tid & 3) * 32 + 16) ^ ((sr & 7) << 4);

  f32x4 acc[4][3] = {};
  f32x4 xr[4];
  #pragma unroll
  for (int j = 0; j < 4; ++j) xr[j] = *(const f32x4*)(xp + j * 4);
  auto pack_write = [&](int buf) {
    u32x4 gA = { pack2(xr[0].x, xr[0].y), pack2(xr[0].z, xr[0].w),
                 pack2(xr[1].x, xr[1].y), pack2(xr[1].z, xr[1].w) };
    u32x4 gB = { pack2(xr[2].x, xr[2].y), pack2(xr[2].z, xr[2].w),
                 pack2(xr[3].x, xr[3].y), pack2(xr[3].z, xr[3].w) };
    *(u32x4*)(xs + buf * 16384 + wbA) = gA;
    *(u32x4*)(xs + buf * 16384 + wbB) = gB;
  };
  pack_write(0);
  __syncthreads();

  const int aswz = (c15 & 7) << 4;
  for (int kt = 0; kt < 16; ++kt) {
    if (kt < 15) {                           // prefetch next x tile (4 loads in flight)
      #pragma unroll
      for (int j = 0; j < 4; ++j) xr[j] = *(const f32x4*)(xp + (kt + 1) * 64 + j * 4);
    }
    s16x8 wf[2][3];                          // all W-frags upfront -> 6 L2 loads in flight
    {
      const unsigned short* wpb = wt3 + (size_t)(n0 + c15) * NC + kt * 64 + g4 * 8;
      #pragma unroll
      for (int ks = 0; ks < 2; ++ks)
        #pragma unroll
        for (int nj = 0; nj < 3; ++nj)
          wf[ks][nj] = *(const s16x8*)(wpb + (size_t)nj * 16 * NC + ks * 32);
    }
    char* cb = xs + (kt & 1) * 16384;
    #pragma unroll
    for (int ks = 0; ks < 2; ++ks) {
      #pragma unroll
      for (int mf = 0; mf < 4; ++mf) {
        int arow = mg * 64 + mf * 16 + c15;
        s16x8 af = *(const s16x8*)(cb + ((arow * 128 + ks * 64 + g4 * 16) ^ aswz));
        #pragma unroll
        for (int nj = 0; nj < 3; ++nj)
          acc[mf][nj] = mfma16(af, wf[ks][nj], acc[mf][nj]);
      }
    }
    if (kt < 15) pack_write((kt + 1) & 1);   // vmcnt wait here, after compute cover
    __syncthreads();
  }
  // epilogue: q,k row-major [M][128]; v transposed [B][128][T]
  #pragma unroll
  for (int mf = 0; mf < 4; ++mf) {
    #pragma unroll
    for (int nj = 0; nj < 3; ++nj) {
      f32x4 a = acc[mf][nj];
      int gcol = n0 + nj * 16 + c15;
      int gr = m0 + mg * 64 + mf * 16 + g4 * 4;
      int h = gcol & 127;
      if (gcol < 256) {
        unsigned short* dst = (gcol < 128) ? qo : ko;
        dst[(size_t)(gr + 0) * NH + h] = f2bf(a.x);
        dst[(size_t)(gr + 1) * NH + h] = f2bf(a.y);
        dst[(size_t)(gr + 2) * NH + h] = f2bf(a.z);
        dst[(size_t)(gr + 3) * NH + h] = f2bf(a.w);
      } else {
        int bb = gr >> 11, tt = gr & 2047;
        u16x4 pv = { f2bf(a.x), f2bf(a.y), f2bf(a.z), f2bf(a.w) };
        *(u16x4*)(vo + ((size_t)(bb * NH + h) * NT + tt)) = pv;
      }
    }
  }
}

// ---------------- kernel 2: flash attention. QBLK=64, kv-split x2, KVBLK=128.
// (unchanged from round 6 — improved there; awaiting its counters next round)
__global__ __launch_bounds__(512, 2) void k_attn(
    const unsigned short* __restrict__ qg, const unsigned short* __restrict__ kg,
    const unsigned short* __restrict__ vg, float* __restrict__ out) {
  __shared__ u32x4 lds4[147456 / 16];        // 144KB
  char* L = (char*)lds4;
  const int tid = threadIdx.x;
  const int lane = tid & 63;
  const int w = tid >> 6;                    // 0..7
  const int grp = w & 1;                     // kv half
  const int qs = w >> 1;                     // q sub-tile (16 rows)
  const int gl = qs * 64 + lane;             // group-local 0..255
  const int b = blockIdx.y;
  const int qr0 = blockIdx.x * 64;
  const int c15 = lane & 15;
  const int g4 = lane >> 4;
  const int kv0 = grp * 1024;

  char* Kg = L + grp * 65536;                // [128 kv][256B] swizzled (32KB)
  char* Vg = Kg + 32768;                     // [128 h][256B kv] swizzled (32KB)
  char* pw = L + 131072 + w * 2048;          // per-wave P [16 q][64 kv] swizzled

  s16x8 qf[4];
  #pragma unroll
  for (int ks = 0; ks < 4; ++ks)
    qf[ks] = *(const s16x8*)(qg + (size_t)(b * NT + qr0 + qs * 16 + c15) * NH + ks * 32 + g4 * 8);

  float m_run[4], lsum[4];
  #pragma unroll
  for (int r = 0; r < 4; ++r) { m_run[r] = -3.0e38f; lsum[r] = 0.0f; }
  f32x4 acc_o[8] = {};

  const int srow = gl >> 4;                  // 0..15 (+16i)
  const unsigned short* kptr = kg + (size_t)(b * NT + kv0 + srow) * NH + (gl & 15) * 8;
  const unsigned short* vptr = vg + (size_t)(b * NH + srow) * NT + kv0 + (gl & 15) * 8;

  u32x4 kreg[8], vreg[8];
  auto stage = [&](int kt) {
    #pragma unroll
    for (int i = 0; i < 8; ++i) {
      kreg[i] = *(const u32x4*)(kptr + ((size_t)(kt * 128 + i * 16)) * NH);
      vreg[i] = *(const u32x4*)(vptr + (size_t)(i * 16) * NT + kt * 128);
    }
  };
  auto write_tiles = [&]() {
    #pragma unroll
    for (int i = 0; i < 8; ++i) {
      int r = srow + i * 16;
      int off = (r * 256 + (gl & 15) * 16) ^ ((r & 7) << 4);
      *(u32x4*)(Kg + off) = kreg[i];
      *(u32x4*)(Vg + off) = vreg[i];
    }
  };
  stage(0);
  write_tiles();
  __syncthreads();

  for (int kt = 0; kt < 8; ++kt) {
    if (kt < 7) stage(kt + 1);               // 16x16B in flight across compute
    // S = Q K^T -> [16 q][128 kv]
    f32x4 s[8];
    __builtin_amdgcn_s_setprio(1);
    #pragma unroll
    for (int nj = 0; nj < 8; ++nj) {
      f32x4 acc_s = {};
      int kr = nj * 16 + c15;
      int kswz = (kr & 7) << 4;
      #pragma unroll
      for (int ks = 0; ks < 4; ++ks) {
        s16x8 bf = *(const s16x8*)(Kg + ((kr * 256 + ks * 64 + g4 * 16) ^ kswz));
        acc_s = mfma16(qf[ks], bf, acc_s);
      }
      s[nj] = acc_s;
    }
    __builtin_amdgcn_s_setprio(0);
    // online softmax (row in 16-lane group), deferred l
    float alpha[4];
    #pragma unroll
    for (int r = 0; r < 4; ++r) {
      float pm = fmaxf(fmaxf(fmaxf(s[0][r], s[1][r]), fmaxf(s[2][r], s[3][r])),
                       fmaxf(fmaxf(s[4][r], s[5][r]), fmaxf(s[6][r], s[7][r])));
      pm = fmaxf(pm, __shfl_xor(pm, 1));
      pm = fmaxf(pm, __shfl_xor(pm, 2));
      pm = fmaxf(pm, __shfl_xor(pm, 4));
      pm = fmaxf(pm, __shfl_xor(pm, 8));
      float mn = fmaxf(m_run[r], pm);
      alpha[r] = __expf(m_run[r] - mn);
      m_run[r] = mn;
      float psum = 0.0f;
      #pragma unroll
      for (int nj = 0; nj < 8; ++nj) {
        float e = __expf(s[nj][r] - mn);
        s[nj][r] = e;
        psum += e;
      }
      lsum[r] = lsum[r] * alpha[r] + psum;
    }
    #pragma unroll
    for (int hj = 0; hj < 8; ++hj) {
      acc_o[hj][0] *= alpha[0]; acc_o[hj][1] *= alpha[1];
      acc_o[hj][2] *= alpha[2]; acc_o[hj][3] *= alpha[3];
    }
    // two P halves of 64 kv each; P write is wave-local (no barrier)
    #pragma unroll
    for (int half = 0; half < 2; ++half) {
      #pragma unroll
      for (int nj = 0; nj < 4; ++nj) {
        #pragma unroll
        for (int r = 0; r < 4; ++r) {
          int row = g4 * 4 + r;
          *(unsigned short*)(pw + ((row * 128 + (nj * 16 + c15) * 2) ^ ((row & 7) << 4)))
              = f2bf(s[half * 4 + nj][r]);
        }
      }
      __builtin_amdgcn_s_setprio(1);
      #pragma unroll
      for (int ks2 = 0; ks2 < 2; ++ks2) {
        s16x8 pa = *(const s16x8*)(pw + ((c15 * 128 + ks2 * 64 + g4 * 16) ^ ((c15 & 7) << 4)));
        int vcb = (half * 2 + ks2) * 64 + g4 * 16;
        #pragma unroll
        for (int hj = 0; hj < 8; ++hj) {
          int vr = hj * 16 + c15;
          s16x8 bv = *(const s16x8*)(Vg + ((vr * 256 + vcb) ^ ((vr & 7) << 4)));
          acc_o[hj] = mfma16(pa, bv, acc_o[hj]);
        }
      }
      __builtin_amdgcn_s_setprio(0);
    }
    __syncthreads();                         // all waves done with K/V
    if (kt < 7) write_tiles();               // vmcnt wait (covered by compute)
    __syncthreads();
  }
  // finish deferred l
  float l_run[4];
  #pragma unroll
  for (int r = 0; r < 4; ++r) {
    float ls = lsum[r];
    ls += __shfl_xor(ls, 1);
    ls += __shfl_xor(ls, 2);
    ls += __shfl_xor(ls, 4);
    ls += __shfl_xor(ls, 8);
    l_run[r] = ls;
  }
  // 2-way merge through LDS
  float* msh = (float*)(L + 131072);         // 64 rows
  float* lsh = msh + 64;
  if (grp == 1) {
    #pragma unroll
    for (int r = 0; r < 4; ++r) {
      int row = qs * 16 + g4 * 4 + r;
      #pragma unroll
      for (int hj = 0; hj < 8; ++hj)
        *(float*)(L + row * 512 + (hj * 16 + c15) * 4) = acc_o[hj][r];
      if (c15 == 0) { msh[row] = m_run[r]; lsh[row] = l_run[r]; }
    }
  }
  __syncthreads();
  if (grp == 0) {
    #pragma unroll
    for (int r = 0; r < 4; ++r) {
      int row = qs * 16 + g4 * 4 + r;
      float m1 = msh[row], l1 = lsh[row];
      float M = fmaxf(m_run[r], m1);
      float w0 = __expf(m_run[r] - M);
      float w1 = __expf(m1 - M);
      float den = 1.0f / (w0 * l_run[r] + w1 * l1);
      #pragma unroll
      for (int hj = 0; hj < 8; ++hj) {
        float o1 = *(const float*)(L + row * 512 + (hj * 16 + c15) * 4);
        out[(size_t)(b * NT + qr0 + row) * NH + hj * 16 + c15] =
            (w0 * acc_o[hj][r] + w1 * o1) * den;
      }
    }
  }
}

extern "C" void kernel_launch(void* const* d_in, const int* in_sizes, int n_in,
                              void* d_out, int out_size, void* d_ws, size_t ws_size,
                              hipStream_t stream) {
  const float* x  = (const float*)d_in[0];
  const float* wq = (const float*)d_in[1];
  const float* wk = (const float*)d_in[2];
  const float* wv = (const float*)d_in[3];
  unsigned short* ws  = (unsigned short*)d_ws;
  unsigned short* qb  = ws;                           // [M][128] bf16   (4MB)
  unsigned short* kb  = ws + (size_t)2 * 1024 * 1024; // [M][128] bf16   (4MB)
  unsigned short* vb  = ws + (size_t)4 * 1024 * 1024; // [B][128][T] bf16 (4MB)
  unsigned short* wt3 = ws + (size_t)6 * 1024 * 1024; // [3][128][1024] bf16 (0.75MB)

  k_prep_w<<<dim3(96), dim3(256), 0, stream>>>(wq, wk, wv, wt3);
  k_qkv<<<dim3(128, 2), dim3(512), 0, stream>>>(x, wt3, qb, kb, vb);
  k_attn<<<dim3(NT / 64, NB), dim3(512), 0, stream>>>(qb, kb, vb, (float*)d_out);
}